// Round 10
// baseline (8966.851 us; speedup 1.0000x reference)
//
#include <hip/hip_runtime.h>
#include <stdint.h>

#define TB     400
#define OUTROW 160000   // T * 2F
#define NTHR   512
#define GRID   256      // (dir 2) x (seq 128), one block per sequence per direction

typedef _Float16 half2_t __attribute__((ext_vector_type(2)));
typedef uint16_t u16;
typedef uint32_t u32;

__device__ __forceinline__ float sigf(float x){ return 1.0f/(1.0f+__expf(-x)); }
__device__ __forceinline__ float tanhf_(float x){ float e=__expf(2.0f*x); return 1.0f-2.0f/(e+1.0f); }
__device__ __forceinline__ u16 h16(float x){ _Float16 h=(_Float16)x; return __builtin_bit_cast(u16,h); }

// fp16 pair MAC with f32 accumulate -> v_fma_mix_f32 pair (full-rate VALU)
__device__ __forceinline__ float fmix2(u32 wu, u32 xu, float acc){
  half2_t w = __builtin_bit_cast(half2_t, wu);
  half2_t x = __builtin_bit_cast(half2_t, xu);
  acc += (float)w.x * (float)x.x;
  acc += (float)w.y * (float)x.y;
  return acc;
}

// xp u16 layout (304 halves = 38 uint4): k 0..99 = x(t), 100..299 = m(t-1), 300..303 = ZERO pad.
// Gates (tid<400): thread owns column c, K=304 in 38 uint4 regs (rows 300..303 staged as 0).
// Phase B (per wave, redundant): lanes 0..49 do cells (lane, lane+50) with cs in regs;
//   h -> wave-private bank hw[wv]; proj col = wv*25+(lane>>1), khalf = lane&1.
// x(t+1): tid 400..499 prefetch + u16-pack into xp in phase B.

__global__ __launch_bounds__(NTHR, 2)
void lstm_v9(const float* __restrict__ z,
             const float* __restrict__ c0f, const float* __restrict__ m0f,
             const float* __restrict__ c0b, const float* __restrict__ m0b,
             const float* __restrict__ Wf, const float* __restrict__ bfv,
             const float* __restrict__ Pf,
             const float* __restrict__ Wb, const float* __restrict__ bbv,
             const float* __restrict__ Pb,
             float* __restrict__ out)
{
  __shared__ __align__(16) u32 xp[152];      // u16[304]
  __shared__ float ga[400];                  // activated gates
  __shared__ __align__(16) u32 hw[8][56];    // per-wave h banks: khalf k at words [28k,28k+25)

  const int tid  = threadIdx.x;
  const int wv   = tid >> 6, lane = tid & 63;
  const int dir  = blockIdx.x >> 7;
  const int seq  = blockIdx.x & 127;

  const float* W   = dir ? Wb  : Wf;
  const float* bv  = dir ? bbv : bfv;
  const float* P   = dir ? Pb  : Pf;
  const float* c0v = dir ? c0b : c0f;
  const float* m0v = dir ? m0b : m0f;

  // ---- gates weights: column c, 38 uint4 (f16-pair packed); rows >=300 are ZERO ----
  const int c = tid;
  const int gate = c / 100;
  uint4 wg[38];
  float bc = 0.f;
  if (c < 400) {
    #pragma unroll
    for (int q = 0; q < 38; ++q) {
      float f[8];
      #pragma unroll
      for (int e = 0; e < 8; ++e) {
        int kk = 8*q + e;
        f[e] = (kk < 300) ? W[(size_t)kk*400 + c] : 0.f;   // R9 bug: guard was missing (OOB read)
      }
      wg[q] = make_uint4((u32)h16(f[0])|((u32)h16(f[1])<<16),
                         (u32)h16(f[2])|((u32)h16(f[3])<<16),
                         (u32)h16(f[4])|((u32)h16(f[5])<<16),
                         (u32)h16(f[6])|((u32)h16(f[7])<<16));
    }
    bc = bv[c] + (gate == 2 ? 1.0f : 0.0f);
  }

  // ---- proj weights: lanes<50 of every wave: col fc = wv*25+(lane>>1), khalf = lane&1 ----
  const int colL = lane >> 1, khalf = lane & 1;
  const int fc = wv*25 + colL;
  u32 pw[25];
  if (lane < 50) {
    #pragma unroll
    for (int j = 0; j < 25; ++j) {
      int k0 = khalf*50 + 2*j;
      pw[j] = (u32)h16(P[(size_t)k0*200 + fc]) | ((u32)h16(P[(size_t)(k0+1)*200 + fc]) << 16);
    }
  }

  // ---- cell state, replicated per wave (lanes 0..49 own cells lane, lane+50) ----
  float cs0 = 0.f, cs1 = 0.f;
  if (lane < 50) {
    cs0 = c0v[(size_t)seq*100 + lane];
    cs1 = c0v[(size_t)seq*100 + 50 + lane];
  }

  // ---- init xp: x(t0) + m0 as u16; ZERO the K pad 300..303 (R9 bug: left garbage) ----
  {
    const int tt0 = dir ? (TB-1) : 0;
    if (tid < 100)       ((u16*)xp)[tid] = h16(z[(size_t)seq*40000 + (size_t)tt0*100 + tid]);
    else if (tid < 300)  ((u16*)xp)[tid] = h16(m0v[(size_t)seq*200 + (tid-100)]);
    else if (tid < 304)  ((u16*)xp)[tid] = (u16)0;
  }
  __syncthreads();

  for (int t = 0; t < TB; ++t) {
    const int tt = dir ? (TB-1-t) : t;

    // x(t+1) prefetch (tid 400..499) — issued first, consumed in phase B
    float xpre = 0.f;
    if (tid >= 400 && tid < 500 && t+1 < TB) {
      const int tn = dir ? (TB-2-t) : (t+1);
      xpre = z[(size_t)seq*40000 + (size_t)tn*100 + (tid-400)];
    }

    // ---- phase A: gates, full-K fma_mix, fused activation ----
    if (c < 400) {
      float a0=0.f, a1=0.f, a2=0.f, a3=0.f;
      const uint4* xp4 = (const uint4*)xp;
      #pragma unroll
      for (int q = 0; q < 38; ++q) {
        uint4 xv = xp4[q];
        a0 = fmix2(wg[q].x, xv.x, a0);
        a1 = fmix2(wg[q].y, xv.y, a1);
        a2 = fmix2(wg[q].z, xv.z, a2);
        a3 = fmix2(wg[q].w, xv.w, a3);
      }
      float a = ((a0+a1)+(a2+a3)) + bc;
      float arg = (gate == 1) ? a+a : a;       // tanh(x) = 2*sig(2x)-1
      float v = sigf(arg);
      ga[c] = (gate == 1) ? 2.0f*v - 1.0f : v;
    }
    __syncthreads();                           // B1: ga ready

    // ---- phase B: per-wave redundant cell + proj + packs (no barrier inside) ----
    if (lane < 50) {
      float I0=ga[lane],    J0=ga[100+lane], F0=ga[200+lane], O0=ga[300+lane];
      float I1=ga[50+lane], J1=ga[150+lane], F1=ga[250+lane], O1=ga[350+lane];
      cs0 = F0*cs0 + I0*J0;
      cs1 = F1*cs1 + I1*J1;
      float h0 = O0*tanhf_(cs0);
      float h1 = O1*tanhf_(cs1);
      u16* hb = (u16*)hw[wv];
      hb[lane]      = h16(h0);                 // bank0: words [0,25)
      hb[56 + lane] = h16(h1);                 // bank1: words [28,53)
      // proj: own-wave h bank, khalf slice, 25 u32 = 6 uint4 + 1 u32
      const u32* hbk = hw[wv] + 28*khalf;
      float p0=0.f, p1=0.f;
      #pragma unroll
      for (int q = 0; q < 6; ++q) {
        uint4 hv = *(const uint4*)(hbk + 4*q);
        p0 = fmix2(pw[4*q+0], hv.x, p0);
        p1 = fmix2(pw[4*q+1], hv.y, p1);
        p0 = fmix2(pw[4*q+2], hv.z, p0);
        p1 = fmix2(pw[4*q+3], hv.w, p1);
      }
      p0 = fmix2(pw[24], hbk[24], p0);
      float p = p0 + p1;
      float m = p + __shfl_xor(p, 1);          // join k-halves (lane pair)
      if (khalf == 0) {
        __builtin_nontemporal_store(m, out + (size_t)seq*OUTROW + (size_t)tt*400 + dir*200 + fc);
        ((u16*)xp)[100 + fc] = h16(m);         // m -> next step's xp
      }
    }
    if (tid >= 400 && tid < 500 && t+1 < TB)
      ((u16*)xp)[tid-400] = h16(xpre);         // x(t+1) -> xp
    __syncthreads();                           // B2: xp ready for next step
  }
}

extern "C" void kernel_launch(void* const* d_in, const int* in_sizes, int n_in,
                              void* d_out, int out_size, void* d_ws, size_t ws_size,
                              hipStream_t stream) {
  (void)in_sizes; (void)n_in; (void)out_size; (void)d_ws; (void)ws_size;
  lstm_v9<<<GRID, NTHR, 0, stream>>>((const float*)d_in[0],
      (const float*)d_in[1], (const float*)d_in[2],
      (const float*)d_in[3], (const float*)d_in[4],
      (const float*)d_in[5], (const float*)d_in[6], (const float*)d_in[7],
      (const float*)d_in[8], (const float*)d_in[9], (const float*)d_in[10],
      (float*)d_out);
}

// Round 11
// 513.079 us; speedup vs baseline: 17.4766x; 17.4766x over previous
//
#include <hip/hip_runtime.h>
#include <stdint.h>

#define TB     400
#define OUTROW 160000   // T * 2F

typedef _Float16 half2_t __attribute__((ext_vector_type(2)));
typedef uint16_t u16;
typedef uint32_t u32;

#if defined(__has_builtin)
#  if __has_builtin(__builtin_amdgcn_fdot2)
#    define HAVE_FDOT2 1
#  endif
#endif

__device__ __forceinline__ float sigf(float x){ return 1.0f/(1.0f+__expf(-x)); }
__device__ __forceinline__ float tanhf_(float x){ float e=__expf(2.0f*x); return 1.0f-2.0f/(e+1.0f); }
__device__ __forceinline__ u16 h16(float x){ _Float16 h=(_Float16)x; return __builtin_bit_cast(u16,h); }
__device__ __forceinline__ u32 pk2(float a, float b){ return (u32)h16(a) | ((u32)h16(b)<<16); }
__device__ __forceinline__ float f16f(u16 u){ return (float)__builtin_bit_cast(_Float16,u); }
__device__ __forceinline__ float dot2f(u32 w, u32 x, float acc){
#ifdef HAVE_FDOT2
  return __builtin_amdgcn_fdot2(__builtin_bit_cast(half2_t,w), __builtin_bit_cast(half2_t,x), acc, false);
#else
  half2_t a = __builtin_bit_cast(half2_t,w), b = __builtin_bit_cast(half2_t,x);
  return acc + (float)a.x*(float)b.x + (float)a.y*(float)b.y;
#endif
}

// ---------- k_q: Q = P @ W_m (100x400 per dir), f16 k-pair packed, rows 100..103 = 0 ----
__global__ __launch_bounds__(512)
void k_q(const float* __restrict__ Wf, const float* __restrict__ Pf,
         const float* __restrict__ Wb, const float* __restrict__ Pb,
         u32* __restrict__ Qp)
{
  const int b = blockIdx.x, dir = b/52, j = b%52, tid = threadIdx.x;
  const float* W = dir?Wb:Wf; const float* P = dir?Pb:Pf;
  __shared__ float pr[2][200];
  for (int i=tid;i<400;i+=512){ int u=i/200,k=i%200; int hk=2*j+u;
    pr[u][k] = (hk<100)? P[(size_t)hk*200+k] : 0.f; }
  __syncthreads();
  if (tid<400){
    float a0=0.f,a1=0.f;
    for (int k=0;k<200;++k){ float w = W[(size_t)(100+k)*400+tid]; a0 += pr[0][k]*w; a1 += pr[1][k]*w; }
    Qp[(size_t)(dir*52+j)*400+tid] = pk2(a0,a1);
  }
}

// ---------- k_m0: M0W[dir][seq][c] = m0 @ W_m  (first-step recurrent term, f32) ----------
__global__ __launch_bounds__(512)
void k_m0(const float* __restrict__ m0f, const float* __restrict__ m0b,
          const float* __restrict__ Wf, const float* __restrict__ Wb,
          float* __restrict__ M0W)
{
  const int b = blockIdx.x, dir=b>>7, seq=b&127, tid=threadIdx.x;
  const float* m0 = dir?m0b:m0f; const float* W = dir?Wb:Wf;
  __shared__ float mr[200];
  if (tid<200) mr[tid] = m0[(size_t)seq*200+tid];
  __syncthreads();
  if (tid<400){
    float a=0.f;
    for (int k=0;k<200;++k) a += mr[k]*W[(size_t)(100+k)*400+tid];
    M0W[(size_t)b*400+tid] = a;
  }
}

// ---------- k_g: Gh[dir][row=seq*400+t][c] = f16( x@Wx + bias(+1 on f) [+ M0W @ first t] ) ----
__global__ __launch_bounds__(512)
void k_g(const float* __restrict__ z,
         const float* __restrict__ Wf, const float* __restrict__ bf,
         const float* __restrict__ Wb, const float* __restrict__ bb,
         const float* __restrict__ M0W, u16* __restrict__ Gh)
{
  const int b=blockIdx.x, dir=b/3200, tile=b%3200, tid=threadIdx.x;
  const int row0 = tile*16;
  const float* W = dir?Wb:Wf; const float* bv = dir?bb:bf;
  __shared__ u32 xr[16][50];
  for (int i=tid;i<800;i+=512){ int rr=i/50, jj=i%50;
    const float* zp = z + (size_t)(row0+rr)*100 + 2*jj;
    xr[rr][jj] = pk2(zp[0], zp[1]); }
  __syncthreads();
  if (tid<400){
    u32 wc[50];
    #pragma unroll
    for (int jj=0;jj<50;++jj)
      wc[jj] = pk2(W[(size_t)(2*jj)*400+tid], W[(size_t)(2*jj+1)*400+tid]);
    const float bc = bv[tid] + ((tid/100)==2 ? 1.0f : 0.0f);
    const int tfirst = dir? (TB-1) : 0;
    for (int rr=0;rr<16;++rr){
      float a0=0.f,a1=0.f;
      #pragma unroll
      for (int jj=0;jj<50;jj+=2){ a0 = dot2f(wc[jj], xr[rr][jj], a0);
                                  a1 = dot2f(wc[jj+1], xr[rr][jj+1], a1); }
      float a = a0+a1+bc;
      int row = row0+rr, t = row%400;
      if (t==tfirst) a += M0W[(size_t)(dir*128 + row/400)*400 + tid];
      Gh[((size_t)dir*51200 + row)*400 + tid] = h16(a);
    }
  }
}

// ---------- k_rec: recurrence. gates(t)=G(t)+h(t-1)@Q ; proj m(t-1)=h(t-1)@P off-path ----
// Roles: tid<400 gates col; 448<=tid<648 proj col; tid<100 cell (phase B). 2 barriers/step.
__global__ __launch_bounds__(704)
void k_rec(const float* __restrict__ c0f, const float* __restrict__ c0b,
           const float* __restrict__ Pf, const float* __restrict__ Pb,
           const u32* __restrict__ Qp, const u16* __restrict__ Gh,
           float* __restrict__ out)
{
  __shared__ __align__(16) u32 h2[52];   // h f16 pairs: k 0..99 + zero pad 100..103
  __shared__ float ga[400];              // activated gates
  const int tid=threadIdx.x, dir=blockIdx.x>>7, seq=blockIdx.x&127;
  const float* P  = dir?Pb:Pf;
  const float* c0 = dir?c0b:c0f;
  const int c  = tid;
  const int pc = tid-448;

  uint4 wq4[13];                         // Q col, 52 u32 -> arch VGPRs (no parking)
  if (tid<400){
    #pragma unroll
    for (int q=0;q<13;++q){
      wq4[q].x = Qp[(size_t)(dir*52 + 4*q+0)*400 + c];
      wq4[q].y = Qp[(size_t)(dir*52 + 4*q+1)*400 + c];
      wq4[q].z = Qp[(size_t)(dir*52 + 4*q+2)*400 + c];
      wq4[q].w = Qp[(size_t)(dir*52 + 4*q+3)*400 + c];
    }
  }
  uint4 pw4[13];                         // P col, pads (k>=100) zero
  if (tid>=448 && tid<648){
    #pragma unroll
    for (int q=0;q<13;++q){
      u32 r[4];
      #pragma unroll
      for (int u=0;u<4;++u){
        int j = 4*q+u;
        r[u] = (2*j<100)? pk2(P[(size_t)(2*j)*200+pc], P[(size_t)(2*j+1)*200+pc]) : 0u;
      }
      pw4[q] = make_uint4(r[0],r[1],r[2],r[3]);
    }
  }
  float cs=0.f;
  if (tid<100) cs = c0[(size_t)seq*100+tid];
  if (tid<52)  h2[tid]=0u;               // h(-1) = 0 (m0 term folded into G's first slot)
  __syncthreads();

  const size_t gbase = ((size_t)dir*51200 + (size_t)seq*400)*400;
  u16 gnext=0;
  if (tid<400) gnext = Gh[gbase + (size_t)(dir?(TB-1):0)*400 + c];

  for (int t=0;t<=TB;++t){
    // ---- phase A: gates(t) [tid<400] || proj m(t-1) [448<=tid<648] ----
    if (tid<400 && t<TB){
      u16 gcur = gnext;
      if (t+1<TB){ int ttn = dir? (TB-2-t):(t+1); gnext = Gh[gbase + (size_t)ttn*400 + c]; }
      float a0=0.f,a1=0.f,a2=0.f,a3=0.f;
      #pragma unroll
      for (int q=0;q<13;++q){
        uint4 xv = *(const uint4*)(h2+4*q);
        a0=dot2f(wq4[q].x,xv.x,a0); a1=dot2f(wq4[q].y,xv.y,a1);
        a2=dot2f(wq4[q].z,xv.z,a2); a3=dot2f(wq4[q].w,xv.w,a3);
      }
      float a = ((a0+a1)+(a2+a3)) + f16f(gcur);
      const int gate = c/100;
      float arg = (gate==1)? a+a : a;          // tanh(x) = 2*sig(2x)-1
      float v = sigf(arg);
      ga[c] = (gate==1)? 2.0f*v-1.0f : v;
    }
    if (tid>=448 && tid<648 && t>0){
      float p0=0.f,p1=0.f,p2=0.f,p3=0.f;
      #pragma unroll
      for (int q=0;q<13;++q){
        uint4 xv = *(const uint4*)(h2+4*q);
        p0=dot2f(pw4[q].x,xv.x,p0); p1=dot2f(pw4[q].y,xv.y,p1);
        p2=dot2f(pw4[q].z,xv.z,p2); p3=dot2f(pw4[q].w,xv.w,p3);
      }
      float m = (p0+p1)+(p2+p3);
      int tp = dir? (TB-t) : (t-1);            // output slot of step t-1
      __builtin_nontemporal_store(m, out + (size_t)seq*OUTROW + (size_t)tp*400 + dir*200 + pc);
    }
    __syncthreads();
    // ---- phase B: cell update -> h(t) ----
    if (tid<100 && t<TB){
      float I=ga[tid], J=ga[100+tid], F=ga[200+tid], O=ga[300+tid];
      float cc = F*cs + I*J; cs=cc;
      float h = O*tanhf_(cc);
      ((u16*)h2)[tid] = h16(h);
    }
    __syncthreads();
  }
}

extern "C" void kernel_launch(void* const* d_in, const int* in_sizes, int n_in,
                              void* d_out, int out_size, void* d_ws, size_t ws_size,
                              hipStream_t stream) {
  (void)in_sizes; (void)n_in; (void)out_size; (void)ws_size;
  const float* z   = (const float*)d_in[0];
  const float* c0f = (const float*)d_in[1];
  const float* m0f = (const float*)d_in[2];
  const float* c0b = (const float*)d_in[3];
  const float* m0b = (const float*)d_in[4];
  const float* Wf  = (const float*)d_in[5];
  const float* bf  = (const float*)d_in[6];
  const float* Pf  = (const float*)d_in[7];
  const float* Wb  = (const float*)d_in[8];
  const float* bb  = (const float*)d_in[9];
  const float* Pb  = (const float*)d_in[10];

  u32*   Qp  = (u32*)d_ws;                            // 166,400 B
  float* M0W = (float*)((char*)d_ws + 196608);        // 409,600 B
  u16*   Gh  = (u16*)((char*)d_ws + 655360);          // 81,920,000 B  (total ~82.6 MB)

  k_q  <<<104, 512, 0, stream>>>(Wf, Pf, Wb, Pb, Qp);
  k_m0 <<<256, 512, 0, stream>>>(m0f, m0b, Wf, Wb, M0W);
  k_g  <<<6400,512, 0, stream>>>(z, Wf, bf, Wb, bb, M0W, Gh);
  k_rec<<<256, 704, 0, stream>>>(c0f, c0b, Pf, Pb, Qp, Gh, (float*)d_out);
}